// Round 1
// baseline (260.731 us; speedup 1.0000x reference)
//
#include <hip/hip_runtime.h>
#include <hip/hip_bf16.h>
#include <stdint.h>

// Problem: B=4096, I=H=1024. pre_ih = x@w_ih^T, pre_hh = h@w_hh^T (each 4096x4096,
// K=1024), per-gate LN over H, gate math, c_new LN, outputs h_new||c_new (fp32).

#define HDIM 1024
#define BATCH 4096
#define NGATE 4096   /* 4*H */
#define KDIM 1024

typedef __bf16 bf16x8 __attribute__((ext_vector_type(8)));
typedef float f32x4 __attribute__((ext_vector_type(4)));
typedef unsigned short ushort8_t __attribute__((ext_vector_type(8)));

__device__ __forceinline__ unsigned short f2bf(float f) {
  unsigned int u = __builtin_bit_cast(unsigned int, f);
  unsigned int r = (u + 0x7fffu + ((u >> 16) & 1u)) >> 16;
  return (unsigned short)r;
}

__device__ __forceinline__ float bf2f(unsigned short s) {
  unsigned int u = ((unsigned int)s) << 16;
  return __builtin_bit_cast(float, u);
}

__device__ __forceinline__ void gl_lds16(const void* g, void* l) {
  // async global->LDS, 16B per lane; LDS dest = wave-uniform base + lane*16,
  // global addr is per-lane.
  __builtin_amdgcn_global_load_lds(
      (__attribute__((address_space(1))) unsigned int*)g,
      (__attribute__((address_space(3))) unsigned int*)l,
      16, 0, 0);
}

#define BAR() asm volatile("s_barrier" ::: "memory")
#define WAITL() asm volatile("s_waitcnt lgkmcnt(0)" ::: "memory")
#define WAITV(N) asm volatile("s_waitcnt vmcnt(" #N ")" ::: "memory")

// ---------------- cast fp32 -> bf16 (x, h, w_ih, w_hh) ----------------
__global__ __launch_bounds__(256) void cast_bf16_kernel(
    const float* __restrict__ x, const float* __restrict__ h,
    const float* __restrict__ wi, const float* __restrict__ wh,
    unsigned short* __restrict__ xb, unsigned short* __restrict__ hb,
    unsigned short* __restrict__ wib, unsigned short* __restrict__ whb) {
  const float* src;
  unsigned short* dst;
  switch (blockIdx.y) {
    case 0: src = x;  dst = xb;  break;
    case 1: src = h;  dst = hb;  break;
    case 2: src = wi; dst = wib; break;
    default: src = wh; dst = whb; break;
  }
  size_t i = ((size_t)blockIdx.x * 256 + threadIdx.x) * 4;
  float4 v = *(const float4*)(src + i);
  ushort4 o;
  o.x = f2bf(v.x); o.y = f2bf(v.y); o.z = f2bf(v.z); o.w = f2bf(v.w);
  *(ushort4*)(dst + i) = o;
}

// ---------------- bf16 MFMA GEMM: C[m][n] = sum_k A[m][k]*B[n][k] ----------------
// 256x256 tile, BK=64, 8 waves (2M x 4N), 8-phase schedule with counted vmcnt
// (T3+T4) + setprio (T5), on top of the existing fetch-side XOR swizzle (T2,
// measured 0 bank conflicts).
//
// Wave output 128x64, STRIDED halves: frag (i,j) -> row (i>>2)*128 + wr*64 +
// (i&3)*16, col (j>>1)*128 + wc*32 + (j&1)*16. So each phase q=(h,g) touches
// exactly one A-half h=q>>1 and one B-half g=q&1: A0 read at q0,q1 (freed after
// q1), B0 at q0,q2, A1 at q2,q3, B1 at q1,q3.
//
// LDS: per operand 4 half-slots [128][64] (2 tiles double-buffered) = 128 KiB.
// Steady staging (1 half-tile = 2 gl_lds16/wave per phase), targeting freed slots:
//   q0: A1(t+1)   q1: B1(t+1)   q2: A0(t+2)   q3: B0(t+2)
// Per-wave VMEM stream => counted waits (2 loads/half):
//   end q0: vmcnt(6) ensures A1(t),B1(t) landed (needed q1/q2); 3 halves in flight
//   end q3: vmcnt(8) ensures A0(t+1),B0(t+1) landed (needed next q0); 4 in flight
// Prologue issues A0(0),B0(0),A1(0),B1(0),A0(1),B0(1) then vmcnt(8) -> same
// steady-state invariant from t=0. Tail stages wrap k modulo K (write only
// already-freed slots; data never read) to keep the loop branch-free and the
// vmcnt counts uniform.
__global__ __launch_bounds__(512, 2) void gemm_bt_kernel(
    const unsigned short* __restrict__ A0p, const unsigned short* __restrict__ B0p,
    unsigned short* __restrict__ C0p,
    const unsigned short* __restrict__ A1p, const unsigned short* __restrict__ B1p,
    unsigned short* __restrict__ C1p) {
  const unsigned short* A = blockIdx.z ? A1p : A0p;
  const unsigned short* B = blockIdx.z ? B1p : B0p;
  unsigned short* C = blockIdx.z ? C1p : C0p;

  __shared__ alignas(16) unsigned short As[4 * 128 * 64];  // 4 half-slots, 64KB
  __shared__ alignas(16) unsigned short Bs[4 * 128 * 64];  // 4 half-slots, 64KB

  const int tid = threadIdx.x;
  const int wave = tid >> 6;
  const int lane = tid & 63;
  const int wr = wave >> 2;   // 0..1 (M)
  const int wc = wave & 3;    // 0..3 (N)
  const int bm = blockIdx.x * 256;
  const int bn = blockIdx.y * 256;

  // staging: each gl_lds16 covers 8 rows x 128B per wave; 8 waves = 64 rows/call.
  const int srow = lane >> 3;
  const int scol = ((lane & 7) ^ (lane >> 3)) * 8;  // fetch-side swizzle
  const int m15 = lane & 15;
  const int quad = lane >> 4;
  const int sw = m15 & 7;

  f32x4 acc[8][4];
#pragma unroll
  for (int i = 0; i < 8; ++i)
#pragma unroll
    for (int j = 0; j < 4; ++j)
#pragma unroll
      for (int r = 0; r < 4; ++r) acc[i][j][r] = 0.0f;

  // stage one 128-row half (rows grow0..grow0+127, cols kk..kk+63) into slot
  auto stage = [&](const unsigned short* __restrict__ G, int grow0, int kk,
                   unsigned short* slot) {
    gl_lds16(G + (size_t)(grow0 + wave * 8 + srow) * KDIM + kk + scol,
             slot + wave * 8 * 64);
    gl_lds16(G + (size_t)(grow0 + 64 + wave * 8 + srow) * KDIM + kk + scol,
             slot + (64 + wave * 8) * 64);
  };

  // prologue: A0(0),B0(0),A1(0),B1(0),A0(1),B0(1) = 12 loads/wave
  stage(A, bm,       0,  &As[0]);
  stage(B, bn,       0,  &Bs[0]);
  stage(A, bm + 128, 0,  &As[1 * 8192]);
  stage(B, bn + 128, 0,  &Bs[1 * 8192]);
  stage(A, bm,       64, &As[2 * 8192]);
  stage(B, bn,       64, &Bs[2 * 8192]);
  WAITV(8);   // A0(0),B0(0) resident; 4 halves in flight
  BAR();

  for (int t = 0; t < 16; ++t) {
    const int p2  = (t & 1) * 2;          // this tile's slot pair
    const int n2  = ((t + 1) & 1) * 2;    // next tile's slot pair
    const int kk1 = ((t + 1) & 15) * 64;
    const int kk2 = ((t + 2) & 15) * 64;

#pragma unroll
    for (int q = 0; q < 4; ++q) {
      const int h = q >> 1;   // A-half
      const int g = q & 1;    // B-half

      // ---- ds-load register subtiles (12 x ds_read_b128) ----
      bf16x8 af[4][2], bfr[2][2];
      const unsigned short* Abase = &As[(p2 + h) * 8192];
      const unsigned short* Bbase = &Bs[(p2 + g) * 8192];
#pragma unroll
      for (int i2 = 0; i2 < 4; ++i2) {
        int r = wr * 64 + i2 * 16 + m15;
#pragma unroll
        for (int s = 0; s < 2; ++s)
          af[i2][s] = *(const bf16x8*)&Abase[r * 64 + (((s * 4 + quad) ^ sw) << 3)];
      }
#pragma unroll
      for (int j2 = 0; j2 < 2; ++j2) {
        int r = wc * 32 + j2 * 16 + m15;
#pragma unroll
        for (int s = 0; s < 2; ++s)
          bfr[j2][s] = *(const bf16x8*)&Bbase[r * 64 + (((s * 4 + quad) ^ sw) << 3)];
      }

      // ---- stage 1 half-tile (2 x global_load_lds) into the just-freed slot ----
      if (q == 0)      stage(A, bm + 128, kk1, &As[(n2 + 1) * 8192]);
      else if (q == 1) stage(B, bn + 128, kk1, &Bs[(n2 + 1) * 8192]);
      else if (q == 2) stage(A, bm,       kk2, &As[p2 * 8192]);
      else             stage(B, bn,       kk2, &Bs[p2 * 8192]);

      BAR();
      WAITL();
      __builtin_amdgcn_s_setprio(1);
#pragma unroll
      for (int i2 = 0; i2 < 4; ++i2)
#pragma unroll
        for (int j2 = 0; j2 < 2; ++j2) {
          acc[h * 4 + i2][g * 2 + j2] = __builtin_amdgcn_mfma_f32_16x16x32_bf16(
              af[i2][0], bfr[j2][0], acc[h * 4 + i2][g * 2 + j2], 0, 0, 0);
          acc[h * 4 + i2][g * 2 + j2] = __builtin_amdgcn_mfma_f32_16x16x32_bf16(
              af[i2][1], bfr[j2][1], acc[h * 4 + i2][g * 2 + j2], 0, 0, 0);
        }
      __builtin_amdgcn_s_setprio(0);
      if (q == 0) WAITV(6);   // A1(t),B1(t) landed for q1/q2
      if (q == 3) WAITV(8);   // A0(t+1),B0(t+1) landed for next q0
      BAR();
    }
  }
  WAITV(0);  // drain tail garbage stages before LDS goes out of scope

  // D layout per 16x16 frag: row = quad*4 + rr, col = m15  [m89/m91 verified]
#pragma unroll
  for (int i = 0; i < 8; ++i) {
    int m = bm + (i >> 2) * 128 + wr * 64 + (i & 3) * 16 + quad * 4;
#pragma unroll
    for (int j = 0; j < 4; ++j) {
      int n = bn + (j >> 1) * 128 + wc * 32 + (j & 1) * 16 + m15;
#pragma unroll
      for (int rr = 0; rr < 4; ++rr)
        C[(size_t)(m + rr) * NGATE + n] = f2bf(acc[i][j][rr]);
    }
  }
}

// ---------------- LN + gates + cell update ----------------
// One block per batch row b. Phase A: wave g computes LN stats for gate g
// (ih and hh) via wave-local butterfly reduction (no barriers). Phase B:
// normalize with broadcast stats (re-load is L1/L2-hot), gate math, one block
// reduction for the c_new LN.
__device__ __forceinline__ float fast_sigmoid(float x) {
  return __builtin_amdgcn_rcpf(1.0f + __expf(-x));
}
__device__ __forceinline__ float fast_tanh(float x) {
  // 1 - 2/(exp(2x)+1); exp->inf gives 1, exp->0 gives -1 (correct saturation)
  return 1.0f - 2.0f * __builtin_amdgcn_rcpf(__expf(2.0f * x) + 1.0f);
}

__global__ __launch_bounds__(256) void ln_gate_kernel(
    const unsigned short* __restrict__ pih, const unsigned short* __restrict__ phh,
    const float* __restrict__ c, const float* __restrict__ b_ih,
    const float* __restrict__ gamma, const float* __restrict__ beta,
    float* __restrict__ h_out, float* __restrict__ c_out) {
  __shared__ float lds[32];  // [0..15]: per-gate stats; [16..31]: scratch
  const int b = blockIdx.x;
  const int t = threadIdx.x;
  const int wave = t >> 6;   // = gate index in phase A
  const int lane = t & 63;
  const float inv_h = 1.0f / 1024.0f;
  const float eps = 1e-5f;

  // ---- Phase A: per-gate LN stats, wave-local ----
  {
    const size_t rb = (size_t)b * NGATE + wave * HDIM + lane * 16;
    ushort8_t a0 = *(const ushort8_t*)&pih[rb];
    ushort8_t a1 = *(const ushort8_t*)&pih[rb + 8];
    ushort8_t e0 = *(const ushort8_t*)&phh[rb];
    ushort8_t e1 = *(const ushort8_t*)&phh[rb + 8];
    float s0 = 0.f, q0 = 0.f, s1 = 0.f, q1 = 0.f;
#pragma unroll
    for (int r = 0; r < 8; ++r) {
      float va = bf2f(a0[r]), vb = bf2f(a1[r]);
      float ea = bf2f(e0[r]), eb = bf2f(e1[r]);
      s0 += va + vb; q0 += va * va + vb * vb;
      s1 += ea + eb; q1 += ea * ea + eb * eb;
    }
#pragma unroll
    for (int o = 1; o < 64; o <<= 1) {
      s0 += __shfl_xor(s0, o, 64); q0 += __shfl_xor(q0, o, 64);
      s1 += __shfl_xor(s1, o, 64); q1 += __shfl_xor(q1, o, 64);
    }
    if (lane == 0) {
      float mu0 = s0 * inv_h;
      float mu1 = s1 * inv_h;
      lds[wave * 4 + 0] = mu0;
      lds[wave * 4 + 1] = rsqrtf(q0 * inv_h - mu0 * mu0 + eps);
      lds[wave * 4 + 2] = mu1;
      lds[wave * 4 + 3] = rsqrtf(q1 * inv_h - mu1 * mu1 + eps);
    }
  }
  __syncthreads();

  // ---- Phase B: normalize + gate math + c_new LN ----
  const int j = t * 4;
  float gate[4][4];
#pragma unroll
  for (int g = 0; g < 4; ++g) {
    float mu0 = lds[g * 4 + 0], rs0 = lds[g * 4 + 1];
    float mu1 = lds[g * 4 + 2], rs1 = lds[g * 4 + 3];
    ushort4 a4 = *(const ushort4*)&pih[(size_t)b * NGATE + g * HDIM + j];
    ushort4 e4 = *(const ushort4*)&phh[(size_t)b * NGATE + g * HDIM + j];
    float vih[4] = {bf2f(a4.x), bf2f(a4.y), bf2f(a4.z), bf2f(a4.w)};
    float vhh[4] = {bf2f(e4.x), bf2f(e4.y), bf2f(e4.z), bf2f(e4.w)};
    float4 g0 = *(const float4*)&gamma[(2 * g) * HDIM + j];
    float4 b0 = *(const float4*)&beta[(2 * g) * HDIM + j];
    float4 g1 = *(const float4*)&gamma[(2 * g + 1) * HDIM + j];
    float4 b1 = *(const float4*)&beta[(2 * g + 1) * HDIM + j];
    float4 bb = *(const float4*)&b_ih[g * HDIM + j];
    const float* g0p = &g0.x; const float* b0p = &b0.x;
    const float* g1p = &g1.x; const float* b1p = &b1.x;
    const float* bbp = &bb.x;
#pragma unroll
    for (int r = 0; r < 4; ++r) {
      float gih = g0p[r] * ((vih[r] - mu0) * rs0) + b0p[r];
      float ghh = g1p[r] * ((vhh[r] - mu1) * rs1) + b1p[r];
      gate[g][r] = gih + ghh + bbp[r];
    }
  }

  float4 cv4 = *(const float4*)&c[(size_t)b * HDIM + j];
  const float* cvp = &cv4.x;
  float cn[4], ov[4];
  float s2 = 0.f, q2 = 0.f;
#pragma unroll
  for (int r = 0; r < 4; ++r) {
    float iv = fast_sigmoid(gate[0][r]);
    float fv = fast_sigmoid(gate[1][r]);
    float av = fast_tanh(gate[2][r]);
    ov[r] = fast_sigmoid(gate[3][r]);
    float cvn = fv * cvp[r] + iv * av;
    cn[r] = cvn;
    s2 += cvn; q2 += cvn * cvn;
  }
#pragma unroll
  for (int o = 1; o < 64; o <<= 1) {
    s2 += __shfl_xor(s2, o, 64);
    q2 += __shfl_xor(q2, o, 64);
  }
  __syncthreads();  // stats already consumed into registers
  if (lane == 0) { lds[16 + wave * 2] = s2; lds[16 + wave * 2 + 1] = q2; }
  __syncthreads();
  s2 = lds[16] + lds[18] + lds[20] + lds[22];
  q2 = lds[17] + lds[19] + lds[21] + lds[23];
  float mu = s2 * inv_h;
  float rs = rsqrtf(q2 * inv_h - mu * mu + eps);

  float4 g8 = *(const float4*)&gamma[8 * HDIM + j];
  float4 b8 = *(const float4*)&beta[8 * HDIM + j];
  const float* g8p = &g8.x; const float* b8p = &b8.x;
  float4 ho, co;
  float* hop = &ho.x; float* cop = &co.x;
#pragma unroll
  for (int r = 0; r < 4; ++r) {
    float ln = g8p[r] * ((cn[r] - mu) * rs) + b8p[r];
    hop[r] = ov[r] * fast_tanh(ln);
    cop[r] = cn[r];
  }
  *(float4*)&h_out[(size_t)b * HDIM + j] = ho;
  *(float4*)&c_out[(size_t)b * HDIM + j] = co;
}

extern "C" void kernel_launch(void* const* d_in, const int* in_sizes, int n_in,
                              void* d_out, int out_size, void* d_ws, size_t ws_size,
                              hipStream_t stream) {
  const float* x     = (const float*)d_in[0];
  const float* h     = (const float*)d_in[1];
  const float* c     = (const float*)d_in[2];
  const float* w_ih  = (const float*)d_in[3];
  const float* w_hh  = (const float*)d_in[4];
  const float* b_ih  = (const float*)d_in[5];
  const float* gamma = (const float*)d_in[6];
  const float* beta  = (const float*)d_in[7];
  // d_in[8] = time (unused)

  // workspace layout (bytes):
  //   0    xb  bf16 4096x1024 (8MB) | 8M hb | 16M wib | 24M whb
  //   32M  pih bf16 4096x4096 (32MB) | 64M phh (32MB)   total 96 MB
  char* ws = (char*)d_ws;
  unsigned short* xb  = (unsigned short*)(ws);
  unsigned short* hb  = (unsigned short*)(ws + (size_t)8 * 1024 * 1024);
  unsigned short* wib = (unsigned short*)(ws + (size_t)16 * 1024 * 1024);
  unsigned short* whb = (unsigned short*)(ws + (size_t)24 * 1024 * 1024);
  unsigned short* pih = (unsigned short*)(ws + (size_t)32 * 1024 * 1024);
  unsigned short* phh = (unsigned short*)(ws + (size_t)64 * 1024 * 1024);

  dim3 cgrid(4096, 4, 1);  // 4 arrays x 4M elems, 4 elems/thread
  cast_bf16_kernel<<<cgrid, 256, 0, stream>>>(x, h, w_ih, w_hh, xb, hb, wib, whb);

  dim3 ggrid(16, 16, 2);   // 256x256 tiles over 4096x4096; z: 0=ih, 1=hh
  gemm_bt_kernel<<<ggrid, 512, 0, stream>>>(xb, wib, pih, hb, whb, phh);

  float* h_out = (float*)d_out;
  float* c_out = h_out + (size_t)BATCH * HDIM;
  ln_gate_kernel<<<4096, 256, 0, stream>>>(pih, phh, c, b_ih, gamma, beta, h_out, c_out);
}

// Round 2
// 242.671 us; speedup vs baseline: 1.0744x; 1.0744x over previous
//
#include <hip/hip_runtime.h>
#include <hip/hip_bf16.h>
#include <stdint.h>

// Problem: B=4096, I=H=1024. pre_ih = x@w_ih^T, pre_hh = h@w_hh^T (each 4096x4096,
// K=1024), per-gate LN over H, gate math, c_new LN, outputs h_new||c_new (fp32).

#define HDIM 1024
#define BATCH 4096
#define NGATE 4096   /* 4*H */
#define KDIM 1024

typedef __bf16 bf16x8 __attribute__((ext_vector_type(8)));
typedef float f32x4 __attribute__((ext_vector_type(4)));
typedef unsigned short ushort8_t __attribute__((ext_vector_type(8)));

__device__ __forceinline__ unsigned short f2bf(float f) {
  unsigned int u = __builtin_bit_cast(unsigned int, f);
  unsigned int r = (u + 0x7fffu + ((u >> 16) & 1u)) >> 16;
  return (unsigned short)r;
}

__device__ __forceinline__ float bf2f(unsigned short s) {
  unsigned int u = ((unsigned int)s) << 16;
  return __builtin_bit_cast(float, u);
}

__device__ __forceinline__ void gl_lds16(const void* g, void* l) {
  // async global->LDS, 16B per lane; LDS dest = wave-uniform base + lane*16,
  // global addr is per-lane.
  __builtin_amdgcn_global_load_lds(
      (__attribute__((address_space(1))) unsigned int*)g,
      (__attribute__((address_space(3))) unsigned int*)l,
      16, 0, 0);
}

#define BAR() asm volatile("s_barrier" ::: "memory")
#define WAITL() asm volatile("s_waitcnt lgkmcnt(0)" ::: "memory")
#define WAITV(N) asm volatile("s_waitcnt vmcnt(" #N ")" ::: "memory")

// ---------------- cast fp32 -> bf16 (x, h, w_ih, w_hh) ----------------
__global__ __launch_bounds__(256) void cast_bf16_kernel(
    const float* __restrict__ x, const float* __restrict__ h,
    const float* __restrict__ wi, const float* __restrict__ wh,
    unsigned short* __restrict__ xb, unsigned short* __restrict__ hb,
    unsigned short* __restrict__ wib, unsigned short* __restrict__ whb) {
  const float* src;
  unsigned short* dst;
  switch (blockIdx.y) {
    case 0: src = x;  dst = xb;  break;
    case 1: src = h;  dst = hb;  break;
    case 2: src = wi; dst = wib; break;
    default: src = wh; dst = whb; break;
  }
  size_t i = ((size_t)blockIdx.x * 256 + threadIdx.x) * 4;
  float4 v = *(const float4*)(src + i);
  ushort4 o;
  o.x = f2bf(v.x); o.y = f2bf(v.y); o.z = f2bf(v.z); o.w = f2bf(v.w);
  *(ushort4*)(dst + i) = o;
}

// ---------------- bf16 MFMA GEMM: C[m][n] = sum_k A[m][k]*B[n][k] ----------------
// 256x256 tile, BK=64, 8 waves (2M x 4N), Gray-coded 4-quadrant schedule with
// register fragment reuse (ds_read 24/K-tile/wave, the m201 traffic level),
// counted vmcnt (T4) + setprio (T5) + fetch-side XOR swizzle (T2, 0 conflicts).
//
// Quadrant order (Gray): q0(A0,B0) q1(A0,B1) q2(A1,B1) q3(A1,B0).
//   af  loaded q0 (A0, reused q1) and q2 (A1, reused q3): 8 ds_read each
//   b0  loaded q0 (reused q3): 4 ds_read;  b1 loaded q1 (reused q2): 4 ds_read
//   q3 issues ZERO ds_reads. Total 24 b128/wave/K-tile (was 48 -> LDS-bound).
//
// LDS: per operand 4 half-slots [128][64] double-buffered by t parity (128 KiB).
// All stages during iter t write the (t+1)-parity pair; all reads hit the
// t-parity pair -> no intra-iter hazard. Stage order matches read deadlines:
//   q0: A0(t+1)  q1: B0(t+1)  q2: B1(t+1)  q3: A1(t+1)
// Counted waits (2 loads per stage, per-wave stream):
//   end q0: vmcnt(4) -> B1(t) landed (read q1)      [leaves A1(t), A0(t+1)]
//   end q1: vmcnt(4) -> A1(t) landed (read q2)      [leaves A0(t+1), B0(t+1)]
//   end q3: vmcnt(4) -> A0,B0(t+1) landed (read q0) [leaves B1(t+1), A1(t+1)]
// Prologue: stage A0(0),B0(0),B1(0),A1(0); vmcnt(4) -> same invariant at t=0.
// Tail (t=15) stages wrap to k=0 (slots never read; keeps counts uniform).
__global__ __launch_bounds__(512, 2) void gemm_bt_kernel(
    const unsigned short* __restrict__ A0p, const unsigned short* __restrict__ B0p,
    unsigned short* __restrict__ C0p,
    const unsigned short* __restrict__ A1p, const unsigned short* __restrict__ B1p,
    unsigned short* __restrict__ C1p) {
  const unsigned short* A = blockIdx.z ? A1p : A0p;
  const unsigned short* B = blockIdx.z ? B1p : B0p;
  unsigned short* C = blockIdx.z ? C1p : C0p;

  __shared__ alignas(16) unsigned short As[4 * 128 * 64];  // 4 half-slots, 64KB
  __shared__ alignas(16) unsigned short Bs[4 * 128 * 64];  // 4 half-slots, 64KB

  const int tid = threadIdx.x;
  const int wave = tid >> 6;
  const int lane = tid & 63;
  const int wr = wave >> 2;   // 0..1 (M)
  const int wc = wave & 3;    // 0..3 (N)
  const int bm = blockIdx.x * 256;
  const int bn = blockIdx.y * 256;

  // staging: each gl_lds16 covers 8 rows x 128B per wave; 8 waves = 64 rows/call.
  const int srow = lane >> 3;
  const int scol = ((lane & 7) ^ (lane >> 3)) * 8;  // fetch-side swizzle
  const int m15 = lane & 15;
  const int quad = lane >> 4;
  const int sw = m15 & 7;

  // per-wave global staging bases (row = wave*8 + srow within a 64-row block)
  const unsigned short* gwA = A + (size_t)(bm + wave * 8 + srow) * KDIM + scol;
  const unsigned short* gwB = B + (size_t)(bn + wave * 8 + srow) * KDIM + scol;

  f32x4 acc[8][4];
#pragma unroll
  for (int i = 0; i < 8; ++i)
#pragma unroll
    for (int j = 0; j < 4; ++j)
#pragma unroll
      for (int r = 0; r < 4; ++r) acc[i][j][r] = 0.0f;

  // stage one 128-row half (global rows goff..goff+127 at cols kk..kk+63)
  auto stage = [&](const unsigned short* gw, int goff, int kk, unsigned short* slot) {
    gl_lds16(gw + (size_t)goff * KDIM + kk, slot + wave * 512);
    gl_lds16(gw + (size_t)(goff + 64) * KDIM + kk, slot + wave * 512 + 4096);
  };

  // prologue: A0(0), B0(0), B1(0), A1(0) = 8 loads/wave
  stage(gwA, 0,   0, &As[0]);
  stage(gwB, 0,   0, &Bs[0]);
  stage(gwB, 128, 0, &Bs[1 * 8192]);
  stage(gwA, 128, 0, &As[1 * 8192]);
  WAITV(4);   // A0(0),B0(0) resident; B1(0),A1(0) in flight
  BAR();

  for (int t = 0; t < 16; ++t) {
    const int p2  = (t & 1) * 2;          // this tile's slot pair
    const int n2  = ((t + 1) & 1) * 2;    // next tile's slot pair
    const int kk1 = ((t + 1) & 15) * 64;

    const unsigned short* A0b = &As[p2 * 8192];
    const unsigned short* A1b = &As[(p2 + 1) * 8192];
    const unsigned short* B0b = &Bs[p2 * 8192];
    const unsigned short* B1b = &Bs[(p2 + 1) * 8192];

    bf16x8 af[4][2], b0[2][2], b1[2][2];

    // ================= q0: (A0,B0) =================
#pragma unroll
    for (int i2 = 0; i2 < 4; ++i2) {
      int r = wr * 64 + i2 * 16 + m15;
#pragma unroll
      for (int s = 0; s < 2; ++s)
        af[i2][s] = *(const bf16x8*)&A0b[r * 64 + (((s * 4 + quad) ^ sw) << 3)];
    }
#pragma unroll
    for (int j2 = 0; j2 < 2; ++j2) {
      int r = wc * 32 + j2 * 16 + m15;
#pragma unroll
      for (int s = 0; s < 2; ++s)
        b0[j2][s] = *(const bf16x8*)&B0b[r * 64 + (((s * 4 + quad) ^ sw) << 3)];
    }
    stage(gwA, 0, kk1, &As[n2 * 8192]);   // A0(t+1)
    BAR();
    WAITL();
    __builtin_amdgcn_s_setprio(1);
#pragma unroll
    for (int i2 = 0; i2 < 4; ++i2)
#pragma unroll
      for (int j2 = 0; j2 < 2; ++j2) {
        acc[i2][j2] = __builtin_amdgcn_mfma_f32_16x16x32_bf16(
            af[i2][0], b0[j2][0], acc[i2][j2], 0, 0, 0);
        acc[i2][j2] = __builtin_amdgcn_mfma_f32_16x16x32_bf16(
            af[i2][1], b0[j2][1], acc[i2][j2], 0, 0, 0);
      }
    __builtin_amdgcn_s_setprio(0);
    WAITV(4);   // B1(t) landed for q1
    BAR();

    // ================= q1: (A0,B1) =================
#pragma unroll
    for (int j2 = 0; j2 < 2; ++j2) {
      int r = wc * 32 + j2 * 16 + m15;
#pragma unroll
      for (int s = 0; s < 2; ++s)
        b1[j2][s] = *(const bf16x8*)&B1b[r * 64 + (((s * 4 + quad) ^ sw) << 3)];
    }
    stage(gwB, 0, kk1, &Bs[n2 * 8192]);   // B0(t+1)
    BAR();
    WAITL();
    __builtin_amdgcn_s_setprio(1);
#pragma unroll
    for (int i2 = 0; i2 < 4; ++i2)
#pragma unroll
      for (int j2 = 0; j2 < 2; ++j2) {
        acc[i2][2 + j2] = __builtin_amdgcn_mfma_f32_16x16x32_bf16(
            af[i2][0], b1[j2][0], acc[i2][2 + j2], 0, 0, 0);
        acc[i2][2 + j2] = __builtin_amdgcn_mfma_f32_16x16x32_bf16(
            af[i2][1], b1[j2][1], acc[i2][2 + j2], 0, 0, 0);
      }
    __builtin_amdgcn_s_setprio(0);
    WAITV(4);   // A1(t) landed for q2
    BAR();

    // ================= q2: (A1,B1) =================
#pragma unroll
    for (int i2 = 0; i2 < 4; ++i2) {
      int r = wr * 64 + i2 * 16 + m15;
#pragma unroll
      for (int s = 0; s < 2; ++s)
        af[i2][s] = *(const bf16x8*)&A1b[r * 64 + (((s * 4 + quad) ^ sw) << 3)];
    }
    stage(gwB, 128, kk1, &Bs[(n2 + 1) * 8192]);   // B1(t+1)
    BAR();
    WAITL();
    __builtin_amdgcn_s_setprio(1);
#pragma unroll
    for (int i2 = 0; i2 < 4; ++i2)
#pragma unroll
      for (int j2 = 0; j2 < 2; ++j2) {
        acc[4 + i2][2 + j2] = __builtin_amdgcn_mfma_f32_16x16x32_bf16(
            af[i2][0], b1[j2][0], acc[4 + i2][2 + j2], 0, 0, 0);
        acc[4 + i2][2 + j2] = __builtin_amdgcn_mfma_f32_16x16x32_bf16(
            af[i2][1], b1[j2][1], acc[4 + i2][2 + j2], 0, 0, 0);
      }
    __builtin_amdgcn_s_setprio(0);
    BAR();

    // ================= q3: (A1,B0) — zero ds_reads =================
    stage(gwA, 128, kk1, &As[(n2 + 1) * 8192]);   // A1(t+1)
    BAR();
    __builtin_amdgcn_s_setprio(1);
#pragma unroll
    for (int i2 = 0; i2 < 4; ++i2)
#pragma unroll
      for (int j2 = 0; j2 < 2; ++j2) {
        acc[4 + i2][j2] = __builtin_amdgcn_mfma_f32_16x16x32_bf16(
            af[i2][0], b0[j2][0], acc[4 + i2][j2], 0, 0, 0);
        acc[4 + i2][j2] = __builtin_amdgcn_mfma_f32_16x16x32_bf16(
            af[i2][1], b0[j2][1], acc[4 + i2][j2], 0, 0, 0);
      }
    __builtin_amdgcn_s_setprio(0);
    WAITV(4);   // A0(t+1),B0(t+1) landed for next q0
    BAR();
  }
  WAITV(0);  // drain tail wrap-stages before LDS goes out of scope

  // D layout per 16x16 frag: row = quad*4 + rr, col = m15  [m89/m91 verified]
#pragma unroll
  for (int i = 0; i < 8; ++i) {
    int m = bm + (i >> 2) * 128 + wr * 64 + (i & 3) * 16 + quad * 4;
#pragma unroll
    for (int j = 0; j < 4; ++j) {
      int n = bn + (j >> 1) * 128 + wc * 32 + (j & 1) * 16 + m15;
#pragma unroll
      for (int rr = 0; rr < 4; ++rr)
        C[(size_t)(m + rr) * NGATE + n] = f2bf(acc[i][j][rr]);
    }
  }
}

// ---------------- LN + gates + cell update ----------------
// One block per batch row b. Phase A: wave g computes LN stats for gate g
// (ih and hh) via wave-local butterfly reduction (no barriers). Phase B:
// normalize with broadcast stats (re-load is L1/L2-hot), gate math, one block
// reduction for the c_new LN.
__device__ __forceinline__ float fast_sigmoid(float x) {
  return __builtin_amdgcn_rcpf(1.0f + __expf(-x));
}
__device__ __forceinline__ float fast_tanh(float x) {
  // 1 - 2/(exp(2x)+1); exp->inf gives 1, exp->0 gives -1 (correct saturation)
  return 1.0f - 2.0f * __builtin_amdgcn_rcpf(__expf(2.0f * x) + 1.0f);
}

__global__ __launch_bounds__(256) void ln_gate_kernel(
    const unsigned short* __restrict__ pih, const unsigned short* __restrict__ phh,
    const float* __restrict__ c, const float* __restrict__ b_ih,
    const float* __restrict__ gamma, const float* __restrict__ beta,
    float* __restrict__ h_out, float* __restrict__ c_out) {
  __shared__ float lds[32];  // [0..15]: per-gate stats; [16..31]: scratch
  const int b = blockIdx.x;
  const int t = threadIdx.x;
  const int wave = t >> 6;   // = gate index in phase A
  const int lane = t & 63;
  const float inv_h = 1.0f / 1024.0f;
  const float eps = 1e-5f;

  // ---- Phase A: per-gate LN stats, wave-local ----
  {
    const size_t rb = (size_t)b * NGATE + wave * HDIM + lane * 16;
    ushort8_t a0 = *(const ushort8_t*)&pih[rb];
    ushort8_t a1 = *(const ushort8_t*)&pih[rb + 8];
    ushort8_t e0 = *(const ushort8_t*)&phh[rb];
    ushort8_t e1 = *(const ushort8_t*)&phh[rb + 8];
    float s0 = 0.f, q0 = 0.f, s1 = 0.f, q1 = 0.f;
#pragma unroll
    for (int r = 0; r < 8; ++r) {
      float va = bf2f(a0[r]), vb = bf2f(a1[r]);
      float ea = bf2f(e0[r]), eb = bf2f(e1[r]);
      s0 += va + vb; q0 += va * va + vb * vb;
      s1 += ea + eb; q1 += ea * ea + eb * eb;
    }
#pragma unroll
    for (int o = 1; o < 64; o <<= 1) {
      s0 += __shfl_xor(s0, o, 64); q0 += __shfl_xor(q0, o, 64);
      s1 += __shfl_xor(s1, o, 64); q1 += __shfl_xor(q1, o, 64);
    }
    if (lane == 0) {
      float mu0 = s0 * inv_h;
      float mu1 = s1 * inv_h;
      lds[wave * 4 + 0] = mu0;
      lds[wave * 4 + 1] = rsqrtf(q0 * inv_h - mu0 * mu0 + eps);
      lds[wave * 4 + 2] = mu1;
      lds[wave * 4 + 3] = rsqrtf(q1 * inv_h - mu1 * mu1 + eps);
    }
  }
  __syncthreads();

  // ---- Phase B: normalize + gate math + c_new LN ----
  const int j = t * 4;
  float gate[4][4];
#pragma unroll
  for (int g = 0; g < 4; ++g) {
    float mu0 = lds[g * 4 + 0], rs0 = lds[g * 4 + 1];
    float mu1 = lds[g * 4 + 2], rs1 = lds[g * 4 + 3];
    ushort4 a4 = *(const ushort4*)&pih[(size_t)b * NGATE + g * HDIM + j];
    ushort4 e4 = *(const ushort4*)&phh[(size_t)b * NGATE + g * HDIM + j];
    float vih[4] = {bf2f(a4.x), bf2f(a4.y), bf2f(a4.z), bf2f(a4.w)};
    float vhh[4] = {bf2f(e4.x), bf2f(e4.y), bf2f(e4.z), bf2f(e4.w)};
    float4 g0 = *(const float4*)&gamma[(2 * g) * HDIM + j];
    float4 b0 = *(const float4*)&beta[(2 * g) * HDIM + j];
    float4 g1 = *(const float4*)&gamma[(2 * g + 1) * HDIM + j];
    float4 b1 = *(const float4*)&beta[(2 * g + 1) * HDIM + j];
    float4 bb = *(const float4*)&b_ih[g * HDIM + j];
    const float* g0p = &g0.x; const float* b0p = &b0.x;
    const float* g1p = &g1.x; const float* b1p = &b1.x;
    const float* bbp = &bb.x;
#pragma unroll
    for (int r = 0; r < 4; ++r) {
      float gih = g0p[r] * ((vih[r] - mu0) * rs0) + b0p[r];
      float ghh = g1p[r] * ((vhh[r] - mu1) * rs1) + b1p[r];
      gate[g][r] = gih + ghh + bbp[r];
    }
  }

  float4 cv4 = *(const float4*)&c[(size_t)b * HDIM + j];
  const float* cvp = &cv4.x;
  float cn[4], ov[4];
  float s2 = 0.f, q2 = 0.f;
#pragma unroll
  for (int r = 0; r < 4; ++r) {
    float iv = fast_sigmoid(gate[0][r]);
    float fv = fast_sigmoid(gate[1][r]);
    float av = fast_tanh(gate[2][r]);
    ov[r] = fast_sigmoid(gate[3][r]);
    float cvn = fv * cvp[r] + iv * av;
    cn[r] = cvn;
    s2 += cvn; q2 += cvn * cvn;
  }
#pragma unroll
  for (int o = 1; o < 64; o <<= 1) {
    s2 += __shfl_xor(s2, o, 64);
    q2 += __shfl_xor(q2, o, 64);
  }
  __syncthreads();  // stats already consumed into registers
  if (lane == 0) { lds[16 + wave * 2] = s2; lds[16 + wave * 2 + 1] = q2; }
  __syncthreads();
  s2 = lds[16] + lds[18] + lds[20] + lds[22];
  q2 = lds[17] + lds[19] + lds[21] + lds[23];
  float mu = s2 * inv_h;
  float rs = rsqrtf(q2 * inv_h - mu * mu + eps);

  float4 g8 = *(const float4*)&gamma[8 * HDIM + j];
  float4 b8 = *(const float4*)&beta[8 * HDIM + j];
  const float* g8p = &g8.x; const float* b8p = &b8.x;
  float4 ho, co;
  float* hop = &ho.x; float* cop = &co.x;
#pragma unroll
  for (int r = 0; r < 4; ++r) {
    float ln = g8p[r] * ((cn[r] - mu) * rs) + b8p[r];
    hop[r] = ov[r] * fast_tanh(ln);
    cop[r] = cn[r];
  }
  *(float4*)&h_out[(size_t)b * HDIM + j] = ho;
  *(float4*)&c_out[(size_t)b * HDIM + j] = co;
}

extern "C" void kernel_launch(void* const* d_in, const int* in_sizes, int n_in,
                              void* d_out, int out_size, void* d_ws, size_t ws_size,
                              hipStream_t stream) {
  const float* x     = (const float*)d_in[0];
  const float* h     = (const float*)d_in[1];
  const float* c     = (const float*)d_in[2];
  const float* w_ih  = (const float*)d_in[3];
  const float* w_hh  = (const float*)d_in[4];
  const float* b_ih  = (const float*)d_in[5];
  const float* gamma = (const float*)d_in[6];
  const float* beta  = (const float*)d_in[7];
  // d_in[8] = time (unused)

  // workspace layout (bytes):
  //   0    xb  bf16 4096x1024 (8MB) | 8M hb | 16M wib | 24M whb
  //   32M  pih bf16 4096x4096 (32MB) | 64M phh (32MB)   total 96 MB
  char* ws = (char*)d_ws;
  unsigned short* xb  = (unsigned short*)(ws);
  unsigned short* hb  = (unsigned short*)(ws + (size_t)8 * 1024 * 1024);
  unsigned short* wib = (unsigned short*)(ws + (size_t)16 * 1024 * 1024);
  unsigned short* whb = (unsigned short*)(ws + (size_t)24 * 1024 * 1024);
  unsigned short* pih = (unsigned short*)(ws + (size_t)32 * 1024 * 1024);
  unsigned short* phh = (unsigned short*)(ws + (size_t)64 * 1024 * 1024);

  dim3 cgrid(4096, 4, 1);  // 4 arrays x 4M elems, 4 elems/thread
  cast_bf16_kernel<<<cgrid, 256, 0, stream>>>(x, h, w_ih, w_hh, xb, hb, wib, whb);

  dim3 ggrid(16, 16, 2);   // 256x256 tiles over 4096x4096; z: 0=ih, 1=hh
  gemm_bt_kernel<<<ggrid, 512, 0, stream>>>(xb, wib, pih, hb, whb, phh);

  float* h_out = (float*)d_out;
  float* c_out = h_out + (size_t)BATCH * HDIM;
  ln_gate_kernel<<<4096, 256, 0, stream>>>(pih, phh, c, b_ih, gamma, beta, h_out, c_out);
}

// Round 3
// 230.327 us; speedup vs baseline: 1.1320x; 1.0536x over previous
//
#include <hip/hip_runtime.h>
#include <hip/hip_bf16.h>
#include <stdint.h>

// Problem: B=4096, I=H=1024. pre_ih = x@w_ih^T, pre_hh = h@w_hh^T (each 4096x4096,
// K=1024), per-gate LN over H, gate math, c_new LN, outputs h_new||c_new (fp32).

#define HDIM 1024
#define BATCH 4096
#define NGATE 4096   /* 4*H */
#define KDIM 1024

typedef __bf16 bf16x8 __attribute__((ext_vector_type(8)));
typedef float f32x4 __attribute__((ext_vector_type(4)));
typedef unsigned short ushort8_t __attribute__((ext_vector_type(8)));

__device__ __forceinline__ unsigned short f2bf(float f) {
  unsigned int u = __builtin_bit_cast(unsigned int, f);
  unsigned int r = (u + 0x7fffu + ((u >> 16) & 1u)) >> 16;
  return (unsigned short)r;
}

__device__ __forceinline__ float bf2f(unsigned short s) {
  unsigned int u = ((unsigned int)s) << 16;
  return __builtin_bit_cast(float, u);
}

__device__ __forceinline__ void gl_lds16(const void* g, void* l) {
  // async global->LDS, 16B per lane; LDS dest = wave-uniform base + lane*16,
  // global addr is per-lane.
  __builtin_amdgcn_global_load_lds(
      (__attribute__((address_space(1))) unsigned int*)g,
      (__attribute__((address_space(3))) unsigned int*)l,
      16, 0, 0);
}

// ---------------- cast fp32 -> bf16 (x, h, w_ih, w_hh) ----------------
// Grid-stride: 512 blocks x 4 arrays, 32 elems/thread, 32B loads + 16B stores.
__global__ __launch_bounds__(256) void cast_bf16_kernel(
    const float* __restrict__ x, const float* __restrict__ h,
    const float* __restrict__ wi, const float* __restrict__ wh,
    unsigned short* __restrict__ xb, unsigned short* __restrict__ hb,
    unsigned short* __restrict__ wib, unsigned short* __restrict__ whb) {
  const float* src;
  unsigned short* dst;
  switch (blockIdx.y) {
    case 0: src = x;  dst = xb;  break;
    case 1: src = h;  dst = hb;  break;
    case 2: src = wi; dst = wib; break;
    default: src = wh; dst = whb; break;
  }
  size_t base = ((size_t)blockIdx.x * 256 + threadIdx.x) * 8;
  const size_t stride = (size_t)512 * 256 * 8;  // 1M elems per sweep
#pragma unroll
  for (int it = 0; it < 4; ++it) {
    float4 v0 = *(const float4*)(src + base);
    float4 v1 = *(const float4*)(src + base + 4);
    ushort8_t o;
    o[0] = f2bf(v0.x); o[1] = f2bf(v0.y); o[2] = f2bf(v0.z); o[3] = f2bf(v0.w);
    o[4] = f2bf(v1.x); o[5] = f2bf(v1.y); o[6] = f2bf(v1.z); o[7] = f2bf(v1.w);
    *(ushort8_t*)(dst + base) = o;
    base += stride;
  }
}

// ---------------- bf16 MFMA GEMM: C[m][n] = sum_k A[m][k]*B[n][k] ----------------
// BM=BN=128, BK=64 (two 16-MFMA k-steps per barrier-pair -> 32 MFMA/barrier,
// halving the vmcnt(0)-before-s_barrier drain fraction vs BK=32).
// LDS rows are 64 elems (128B = 8 granules of 16B). XOR-swizzle: logical
// granule c of row r stored at position c ^ (r&7). Fetch-side (global col
// permutation per lane, since global_load_lds pins LDS dest to lane*16),
// inverted at ds_read: 16-lane read phases hit 8 four-bank groups x 2 lanes
// = conflict-free (m136: 2-way is free).
// [proven round-0: 70 us both GEMMs, MfmaUtil 42%, 0 bank conflicts, ~2.7
// blocks/CU giving implicit cross-block overlap (m114) -- beats my two
// 256x256 8-phase reconstructions (91-101 us, lockstep-serialized).]
__global__ __launch_bounds__(256, 4) void gemm_bt_kernel(
    const unsigned short* __restrict__ A0, const unsigned short* __restrict__ B0,
    unsigned short* __restrict__ C0,
    const unsigned short* __restrict__ A1, const unsigned short* __restrict__ B1,
    unsigned short* __restrict__ C1) {
  const unsigned short* A = blockIdx.z ? A1 : A0;
  const unsigned short* B = blockIdx.z ? B1 : B0;
  unsigned short* C = blockIdx.z ? C1 : C0;

  __shared__ alignas(16) unsigned short As[128 * 64];
  __shared__ alignas(16) unsigned short Bs[128 * 64];

  const int tid = threadIdx.x;
  const int wave = tid >> 6;
  const int lane = tid & 63;
  const int bm = blockIdx.x * 128;
  const int bn = blockIdx.y * 128;
  const int wm = (wave >> 1) * 64;
  const int wn = (wave & 1) * 64;

  // staging: each inst covers 8 rows x 128B; lane -> row lane>>3, granule
  // (lane&7)^(lane>>3) (fetch-side swizzle; row&7 == lane>>3 since bases are
  // multiples of 8)
  const int srow = lane >> 3;
  const int scol = (((lane & 7) ^ (lane >> 3)) * 8);

  f32x4 acc[4][4];
#pragma unroll
  for (int i = 0; i < 4; ++i)
#pragma unroll
    for (int j = 0; j < 4; ++j)
#pragma unroll
      for (int r = 0; r < 4; ++r) acc[i][j][r] = 0.0f;

  const int m15 = lane & 15;
  const int quad = lane >> 4;

  for (int k0 = 0; k0 < KDIM; k0 += 64) {
#pragma unroll
    for (int t = 0; t < 4; ++t) {
      int R = wave * 32 + t * 8;  // wave-uniform row base
      gl_lds16(A + (size_t)(bm + R + srow) * KDIM + k0 + scol, &As[R * 64]);
      gl_lds16(B + (size_t)(bn + R + srow) * KDIM + k0 + scol, &Bs[R * 64]);
    }
    __syncthreads();

#pragma unroll
    for (int s = 0; s < 2; ++s) {
      bf16x8 af[4], bfr[4];
#pragma unroll
      for (int i = 0; i < 4; ++i) {
        int row = wm + i * 16 + m15;
        af[i] = *(const bf16x8*)&As[row * 64 + (((4 * s + quad) ^ (m15 & 7)) * 8)];
      }
#pragma unroll
      for (int j = 0; j < 4; ++j) {
        int row = wn + j * 16 + m15;
        bfr[j] = *(const bf16x8*)&Bs[row * 64 + (((4 * s + quad) ^ (m15 & 7)) * 8)];
      }
#pragma unroll
      for (int i = 0; i < 4; ++i)
#pragma unroll
        for (int j = 0; j < 4; ++j)
          acc[i][j] = __builtin_amdgcn_mfma_f32_16x16x32_bf16(af[i], bfr[j], acc[i][j], 0, 0, 0);
    }

    __syncthreads();
  }

  // D layout: row m = (lane>>4)*4 + r, col n = lane&15  [m89/m91 verified]
#pragma unroll
  for (int i = 0; i < 4; ++i)
#pragma unroll
    for (int j = 0; j < 4; ++j)
#pragma unroll
      for (int r = 0; r < 4; ++r) {
        int m = bm + wm + i * 16 + quad * 4 + r;
        int n = bn + wn + j * 16 + m15;
        C[(size_t)m * NGATE + n] = f2bf(acc[i][j][r]);
      }
}

// ---------------- LN + gates + cell update ----------------
// One block per batch row b. Phase A: wave g owns gate g; lane owns h-positions
// lane*4 + s*256 (s=0..3). Full 64-lane butterfly gives ALL lanes the LN stats
// (no LDS stats round-trip), normalize in-register, hand normalized gate values
// to phase B via a 16KB LDS buffer (fully contiguous b128 writes/reads -- no
// bank conflicts). Eliminates the 64MB of phase-B global re-reads of pih/phh.
// Phase B: thread t owns h = t*4..t*4+3 across all 4 gates; cell math + one
// block reduction for the c_new LN. 2 syncthreads total (was 3).
__device__ __forceinline__ float fast_sigmoid(float x) {
  return __builtin_amdgcn_rcpf(1.0f + __expf(-x));
}
__device__ __forceinline__ float fast_tanh(float x) {
  // 1 - 2/(exp(2x)+1); exp->inf gives 1, exp->0 gives -1 (correct saturation)
  return 1.0f - 2.0f * __builtin_amdgcn_rcpf(__expf(2.0f * x) + 1.0f);
}

__global__ __launch_bounds__(256) void ln_gate_kernel(
    const unsigned short* __restrict__ pih, const unsigned short* __restrict__ phh,
    const float* __restrict__ c, const float* __restrict__ b_ih,
    const float* __restrict__ gamma, const float* __restrict__ beta,
    float* __restrict__ h_out, float* __restrict__ c_out) {
  __shared__ float gbuf[4][1024];  // normalized gate values (16 KB)
  __shared__ float red[8];         // c_new LN cross-wave partials
  const int b = blockIdx.x;
  const int t = threadIdx.x;
  const int g = t >> 6;    // wave index = gate index in phase A
  const int lane = t & 63;
  const float inv_h = 1.0f / 1024.0f;
  const float eps = 1e-5f;

  // ---- Phase A: per-gate LN stats + normalize, wave-local ----
  {
    const size_t rb = (size_t)b * NGATE + g * HDIM;
    float vih[16], vhh[16];
    float s0 = 0.f, q0 = 0.f, s1 = 0.f, q1 = 0.f;
#pragma unroll
    for (int s = 0; s < 4; ++s) {
      const int hh = lane * 4 + s * 256;
      ushort4 a4 = *(const ushort4*)&pih[rb + hh];
      ushort4 e4 = *(const ushort4*)&phh[rb + hh];
      vih[s * 4 + 0] = bf2f(a4.x); vih[s * 4 + 1] = bf2f(a4.y);
      vih[s * 4 + 2] = bf2f(a4.z); vih[s * 4 + 3] = bf2f(a4.w);
      vhh[s * 4 + 0] = bf2f(e4.x); vhh[s * 4 + 1] = bf2f(e4.y);
      vhh[s * 4 + 2] = bf2f(e4.z); vhh[s * 4 + 3] = bf2f(e4.w);
#pragma unroll
      for (int r = 0; r < 4; ++r) {
        float va = vih[s * 4 + r], ea = vhh[s * 4 + r];
        s0 += va; q0 += va * va;
        s1 += ea; q1 += ea * ea;
      }
    }
#pragma unroll
    for (int o = 1; o < 64; o <<= 1) {
      s0 += __shfl_xor(s0, o, 64); q0 += __shfl_xor(q0, o, 64);
      s1 += __shfl_xor(s1, o, 64); q1 += __shfl_xor(q1, o, 64);
    }
    const float mu0 = s0 * inv_h;
    const float rs0 = rsqrtf(q0 * inv_h - mu0 * mu0 + eps);
    const float mu1 = s1 * inv_h;
    const float rs1 = rsqrtf(q1 * inv_h - mu1 * mu1 + eps);

#pragma unroll
    for (int s = 0; s < 4; ++s) {
      const int hh = lane * 4 + s * 256;
      float4 g0 = *(const float4*)&gamma[(2 * g) * HDIM + hh];
      float4 b0 = *(const float4*)&beta[(2 * g) * HDIM + hh];
      float4 g1 = *(const float4*)&gamma[(2 * g + 1) * HDIM + hh];
      float4 b1 = *(const float4*)&beta[(2 * g + 1) * HDIM + hh];
      float4 bb = *(const float4*)&b_ih[g * HDIM + hh];
      const float* g0p = &g0.x; const float* b0p = &b0.x;
      const float* g1p = &g1.x; const float* b1p = &b1.x;
      const float* bbp = &bb.x;
      float4 out;
      float* op = &out.x;
#pragma unroll
      for (int r = 0; r < 4; ++r) {
        float gih = g0p[r] * ((vih[s * 4 + r] - mu0) * rs0) + b0p[r];
        float ghh = g1p[r] * ((vhh[s * 4 + r] - mu1) * rs1) + b1p[r];
        op[r] = gih + ghh + bbp[r];
      }
      *(float4*)&gbuf[g][hh] = out;  // contiguous across lanes: conflict-free
    }
  }
  __syncthreads();

  // ---- Phase B: gate math + c_new LN ----
  const int j = t * 4;
  float4 iv4 = *(const float4*)&gbuf[0][j];
  float4 fv4 = *(const float4*)&gbuf[1][j];
  float4 av4 = *(const float4*)&gbuf[2][j];
  float4 ov4 = *(const float4*)&gbuf[3][j];
  const float* ivp = &iv4.x; const float* fvp = &fv4.x;
  const float* avp = &av4.x; const float* ovp = &ov4.x;

  float4 cv4 = *(const float4*)&c[(size_t)b * HDIM + j];
  const float* cvp = &cv4.x;
  float cn[4], ov[4];
  float s2 = 0.f, q2 = 0.f;
#pragma unroll
  for (int r = 0; r < 4; ++r) {
    float iv = fast_sigmoid(ivp[r]);
    float fv = fast_sigmoid(fvp[r]);
    float av = fast_tanh(avp[r]);
    ov[r] = fast_sigmoid(ovp[r]);
    float cvn = fv * cvp[r] + iv * av;
    cn[r] = cvn;
    s2 += cvn; q2 += cvn * cvn;
  }
#pragma unroll
  for (int o = 1; o < 64; o <<= 1) {
    s2 += __shfl_xor(s2, o, 64);
    q2 += __shfl_xor(q2, o, 64);
  }
  if (lane == 0) { red[g * 2] = s2; red[g * 2 + 1] = q2; }
  __syncthreads();
  s2 = red[0] + red[2] + red[4] + red[6];
  q2 = red[1] + red[3] + red[5] + red[7];
  float mu = s2 * inv_h;
  float rs = rsqrtf(q2 * inv_h - mu * mu + eps);

  float4 g8 = *(const float4*)&gamma[8 * HDIM + j];
  float4 b8 = *(const float4*)&beta[8 * HDIM + j];
  const float* g8p = &g8.x; const float* b8p = &b8.x;
  float4 ho, co;
  float* hop = &ho.x; float* cop = &co.x;
#pragma unroll
  for (int r = 0; r < 4; ++r) {
    float ln = g8p[r] * ((cn[r] - mu) * rs) + b8p[r];
    hop[r] = ov[r] * fast_tanh(ln);
    cop[r] = cn[r];
  }
  *(float4*)&h_out[(size_t)b * HDIM + j] = ho;
  *(float4*)&c_out[(size_t)b * HDIM + j] = co;
}

extern "C" void kernel_launch(void* const* d_in, const int* in_sizes, int n_in,
                              void* d_out, int out_size, void* d_ws, size_t ws_size,
                              hipStream_t stream) {
  const float* x     = (const float*)d_in[0];
  const float* h     = (const float*)d_in[1];
  const float* c     = (const float*)d_in[2];
  const float* w_ih  = (const float*)d_in[3];
  const float* w_hh  = (const float*)d_in[4];
  const float* b_ih  = (const float*)d_in[5];
  const float* gamma = (const float*)d_in[6];
  const float* beta  = (const float*)d_in[7];
  // d_in[8] = time (unused)

  // workspace layout (bytes):
  //   0    xb  bf16 4096x1024 (8MB) | 8M hb | 16M wib | 24M whb
  //   32M  pih bf16 4096x4096 (32MB) | 64M phh (32MB)   total 96 MB
  char* ws = (char*)d_ws;
  unsigned short* xb  = (unsigned short*)(ws);
  unsigned short* hb  = (unsigned short*)(ws + (size_t)8 * 1024 * 1024);
  unsigned short* wib = (unsigned short*)(ws + (size_t)16 * 1024 * 1024);
  unsigned short* whb = (unsigned short*)(ws + (size_t)24 * 1024 * 1024);
  unsigned short* pih = (unsigned short*)(ws + (size_t)32 * 1024 * 1024);
  unsigned short* phh = (unsigned short*)(ws + (size_t)64 * 1024 * 1024);

  dim3 cgrid(512, 4, 1);   // grid-stride: 4 arrays x 4M elems, 32 elems/thread
  cast_bf16_kernel<<<cgrid, 256, 0, stream>>>(x, h, w_ih, w_hh, xb, hb, wib, whb);

  dim3 ggrid(32, 32, 2);   // 128x128 tiles over 4096x4096; z: 0=ih, 1=hh
  gemm_bt_kernel<<<ggrid, 256, 0, stream>>>(xb, wib, pih, hb, whb, phh);

  float* h_out = (float*)d_out;
  float* c_out = h_out + (size_t)BATCH * HDIM;
  ln_gate_kernel<<<4096, 256, 0, stream>>>(pih, phh, c, b_ih, gamma, beta, h_out, c_out);
}